// Round 2
// baseline (38755.707 us; speedup 1.0000x reference)
//
#include <hip/hip_runtime.h>
#include <math.h>

// Ring-attractor recurrence, round 2: latency-oriented redesign.
// 4 independent SETS x 64 blocks (256 blocks = all CUs). Set s owns 16
// batches; within a set each block owns 4 output neurons, with its 36
// weight rows (W_base + 8 Wa) transposed in LDS. Each set pipelines G=2
// batch sub-groups of 8: the 64-block barrier for group g resolves while
// the other group computes, hiding cross-XCD atomic/visibility latency.
// Per phase: spin(g,t-1) -> reload r_g -> [dot(tid<144) || bump-proj(wave3)]
// -> combine partials -> tanh-leak update -> write r chunk -> post bar(g,t).

#define SETS  4
#define SBLK  64      // blocks per set (barrier participants)
#define G     2       // pipelined batch groups per set
#define GB    8       // batches per group
#define NTHR  256
#define BATCH 64
#define TT    512
#define NN    256
#define ADIM  8
#define IC    4       // neurons per block
#define ROWS  36      // 9 * IC
#define WSTR  40      // W^T row stride (floats): 160 B, float4-aligned
#define RSTR  12      // r^T row stride: 48 B, float4-aligned
#define PSTR  12      // partials stride

__global__ __launch_bounds__(NTHR, 1)
void ring_attractor_kernel(const float* __restrict__ act,     // [64,512,8]
                           const float* __restrict__ r_init,  // [64,256]
                           const float* __restrict__ Wo,      // [256,256]
                           const float* __restrict__ Wa,      // [8,256,256]
                           const float* __restrict__ J0,      // [256,256]
                           const float* __restrict__ Wd7,     // [256,256]
                           float* __restrict__ out,           // r_hist | bump
                           unsigned int* __restrict__ bar)    // [512*8] zeroed
{
  __shared__ float WlT[NN * WSTR];        // W^T[j][row], 40 KB
  __shared__ float RlT[NN * RSTR];        // r^T[j][b],  12 KB (current group)
  __shared__ float part[8 * ROWS * PSTR]; // j-split partial dots, 13.5 KB
  __shared__ float mqlf[ROWS * 9];        // combined dots m[row][b]
  __shared__ float cvec[NN], svec[NN];    // cos/sin columns of W_delta7
  __shared__ float Atl[GB][9];            // A(t) for group batches
  __shared__ float sums[3];               // sum c^2, c*s, s^2

  const int tid = threadIdx.x;
  const int set = blockIdx.x >> 6;        // 0..3
  const int bi  = blockIdx.x & 63;        // 0..63 within set
  const int i0  = bi * IC;                // owned neuron base

  float* out_r = out;
  float* out_b = out + (size_t)BATCH * TT * NN;

  // ---------------- init (once) ----------------
  for (int idx = tid; idx < NN; idx += NTHR) {
    cvec[idx] = Wd7[idx * NN];            // cos(2*pi*i/N)
    svec[idx] = Wd7[idx * NN + 64];       // sin(2*pi*i/N)
  }
  for (int idx = tid; idx < ROWS * NN; idx += NTHR) {
    const int row = idx >> 8;             // 0..35
    const int j   = idx & 255;            // coalesced along j
    const int il  = row / 9;
    const int mat = row % 9;
    const int gi  = i0 + il;
    float w;
    if (mat == 0) w = J0[gi * NN + j] + 0.1f * Wo[gi * NN + j];   // J0 + J1*Wo
    else          w = Wa[((size_t)(mat - 1) * NN + gi) * NN + j];
    WlT[j * WSTR + row] = w;              // transposed store (init-only)
  }
  __syncthreads();
  if (tid == 0) {
    float scc = 0.f, scs = 0.f, sss = 0.f;
    for (int j = 0; j < NN; ++j) {
      const float c = cvec[j], s = svec[j];
      scc += c * c; scs += c * s; sss += s * s;
    }
    sums[0] = scc; sums[1] = scs; sums[2] = sss;
  }

  // ---------------- phase loop ----------------
  // t in [0,TT]: at phase (g,t<TT) compute r_hist[:,t,:] for group g;
  // also emit bump[:,t-1,:] (needs the full exchanged r from t-1).
  for (int t = 0; t <= TT; ++t) {
    for (int g = 0; g < G; ++g) {
      const int gb0 = set * (G * GB) + g * GB;  // first global batch of group
      __syncthreads();                          // protect RlT/part reuse
      if (t > 0) {
        if (tid == 0) {
          const unsigned idxb = (unsigned)(((t - 1) * SETS + set) * G + g);
          while (__hip_atomic_load(&bar[idxb], __ATOMIC_ACQUIRE,
                                   __HIP_MEMORY_SCOPE_AGENT) < (unsigned)SBLK)
            __builtin_amdgcn_s_sleep(1);
        }
        __syncthreads();
        __threadfence();
      }

      // reload r(t) for this group (t==0: r_init, else r_hist[:, t-1, :])
      for (int q = tid; q < GB * 64; q += NTHR) {
        const int b  = q & 7;
        const int j4 = q >> 3;
        const float* src = (t == 0)
            ? (r_init + (size_t)(gb0 + b) * NN)
            : (out_r + ((size_t)(gb0 + b) * TT + (t - 1)) * NN);
        const float4 v = *(const float4*)(src + j4 * 4);
        const int j = j4 * 4;
        RlT[(j + 0) * RSTR + b] = v.x;
        RlT[(j + 1) * RSTR + b] = v.y;
        RlT[(j + 2) * RSTR + b] = v.z;
        RlT[(j + 3) * RSTR + b] = v.w;
      }
      if (t < TT && tid < GB * ADIM) {
        const int b = tid >> 3, a = tid & 7;
        Atl[b][a] = act[((size_t)(gb0 + b) * TT + t) * ADIM + a];
      }
      __syncthreads();

      // dot phase (threads 0..143) || bump projection (wave 3), concurrent
      if (t < TT && tid < 144) {
        const int jt  = tid / 18;      // j segment 0..7
        const int rem = tid % 18;
        const int rt  = rem >> 1;      // row tile 0..8 (4 rows each)
        const int bt  = rem & 1;       // batch tile 0..1 (4 batches each)
        float acc[4][4] = {{0.f, 0.f, 0.f, 0.f}, {0.f, 0.f, 0.f, 0.f},
                           {0.f, 0.f, 0.f, 0.f}, {0.f, 0.f, 0.f, 0.f}};
        #pragma unroll 8
        for (int jj = 0; jj < 32; ++jj) {
          const int j = jt * 32 + ((jj + jt) & 31);   // stagger: bank spread
          const float4 w = *(const float4*)&WlT[j * WSTR + rt * 4];
          const float4 x = *(const float4*)&RlT[j * RSTR + bt * 4];
          acc[0][0] += w.x * x.x; acc[0][1] += w.x * x.y;
          acc[0][2] += w.x * x.z; acc[0][3] += w.x * x.w;
          acc[1][0] += w.y * x.x; acc[1][1] += w.y * x.y;
          acc[1][2] += w.y * x.z; acc[1][3] += w.y * x.w;
          acc[2][0] += w.z * x.x; acc[2][1] += w.z * x.y;
          acc[2][2] += w.z * x.z; acc[2][3] += w.z * x.w;
          acc[3][0] += w.w * x.x; acc[3][1] += w.w * x.y;
          acc[3][2] += w.w * x.z; acc[3][3] += w.w * x.w;
        }
        #pragma unroll
        for (int k = 0; k < 4; ++k) {
          float4 v; v.x = acc[k][0]; v.y = acc[k][1];
          v.z = acc[k][2]; v.w = acc[k][3];
          *(float4*)&part[(jt * ROWS + rt * 4 + k) * PSTR + bt * 4] = v;
        }
      } else if (t > 0 && tid >= 192) {
        // bump for step t-1 from the just-reloaded full r(t) of this group
        const int lane = tid - 192;
        const int b = lane >> 3, seg = lane & 7;
        float C = 0.f, S = 0.f;
        #pragma unroll 8
        for (int jj = 0; jj < 32; ++jj) {
          const int j = seg * 32 + ((jj + seg) & 31);
          const float rv = RlT[j * RSTR + b];
          C += cvec[j] * rv;
          S += svec[j] * rv;
        }
        C += __shfl_xor(C, 1); C += __shfl_xor(C, 2); C += __shfl_xor(C, 4);
        S += __shfl_xor(S, 1); S += __shfl_xor(S, 2); S += __shfl_xor(S, 4);
        if (seg < IC) {
          const float n2  = sums[0] * C * C + 2.f * sums[1] * C * S
                          + sums[2] * S * S;
          const float inv = 1.0f / sqrtf(n2);
          out_b[((size_t)(gb0 + b) * TT + (t - 1)) * NN + i0 + seg] =
              (cvec[i0 + seg] * C + svec[i0 + seg] * S) * inv;
        }
      }
      __syncthreads();

      if (t < TT) {
        // combine j-split partials -> m[row][b]
        for (int d = tid; d < ROWS * GB; d += NTHR) {
          const int row = d >> 3, b = d & 7;
          float s = 0.f;
          #pragma unroll
          for (int jt = 0; jt < 8; ++jt)
            s += part[(jt * ROWS + row) * PSTR + b];
          mqlf[row * 9 + b] = s;
        }
        __syncthreads();
        // tanh-leak update + publish r chunk (wave 0 only -> fence covers it)
        if (tid < IC * GB) {
          const int b = tid & 7, il = tid >> 3;
          float rec = mqlf[(il * 9) * 9 + b];
          #pragma unroll
          for (int a = 0; a < ADIM; ++a)
            rec += Atl[b][a] * mqlf[(il * 9 + 1 + a) * 9 + b];
          const int gi = i0 + il;
          const float rold = RlT[gi * RSTR + b];
          const float rnew = rold + 0.1f * (tanhf(rec) - rold);  // DT/TAU=0.1
          out_r[((size_t)(gb0 + b) * TT + t) * NN + gi] = rnew;
        }
        __threadfence();
        if (tid == 0) {
          const unsigned idxb = (unsigned)((t * SETS + set) * G + g);
          __hip_atomic_fetch_add(&bar[idxb], 1u, __ATOMIC_ACQ_REL,
                                 __HIP_MEMORY_SCOPE_AGENT);
        }
      }
    }
  }
}

extern "C" void kernel_launch(void* const* d_in, const int* in_sizes, int n_in,
                              void* d_out, int out_size, void* d_ws, size_t ws_size,
                              hipStream_t stream) {
  const float* act    = (const float*)d_in[0];
  const float* r_init = (const float*)d_in[1];
  const float* Wo     = (const float*)d_in[2];
  const float* Wa     = (const float*)d_in[3];
  const float* J0     = (const float*)d_in[4];
  const float* Wd7    = (const float*)d_in[5];
  float* out = (float*)d_out;
  unsigned int* bar = (unsigned int*)d_ws;

  // zero the per-(t,set,g) barrier counters (ws re-poisoned each launch)
  hipMemsetAsync(d_ws, 0, TT * SETS * G * sizeof(unsigned int), stream);

  hipLaunchKernelGGL(ring_attractor_kernel, dim3(SETS * SBLK), dim3(NTHR), 0,
                     stream, act, r_init, Wo, Wa, J0, Wd7, out, bar);
}

// Round 4
// 6233.923 us; speedup vs baseline: 6.2169x; 6.2169x over previous
//
#include <hip/hip_runtime.h>
#include <math.h>

// Round 4 (= round 3 resubmit + fixes): sync-free batch partition.
// 64 blocks, block b owns batch b for the whole T=512 recurrence; full r
// state is block-local (LDS). Weights are pre-converted once to RNE fp16
// and tiled in d_ws as [group][kchunk][lane] uint4 (group = 64 consecutive
// rows of the 2304-row stack [W_base; Wa 0..7]), so the per-step stream is
// fully-coalesced 1-KB wave loads and each lane accumulates its own row dot
// privately. No inter-block sync anywhere.
// Fixes vs round 3: build grid 288 (was 1152 -> OOB), fp16 weights (was
// bf16) for ~16x better quantization error at identical cost.

#define BATCH 64
#define TT    512
#define NN    256
#define ADIM  8
#define NMAT  9               // W_base + 8 Wa
#define ROWS  (NMAT * NN)     // 2304
#define GROUPS (ROWS / 64)    // 36
#define NTHR  576             // 9 waves; wave w owns groups 4w..4w+3
#define KC    32              // 32 column-chunks of 8

// ---------------- pre-pass: build tiled fp16 weights in ws ----------------
__global__ __launch_bounds__(256)
void build_wt_kernel(const float* __restrict__ Wo,
                     const float* __restrict__ Wa,
                     const float* __restrict__ J0,
                     uint4* __restrict__ Wt)
{
  const int q    = blockIdx.x * 256 + threadIdx.x;  // 0..73727
  const int lane = q & 63;
  const int kc   = (q >> 6) & 31;
  const int g    = q >> 11;                          // 0..35
  const int row  = g * 64 + lane;                    // 0..2303
  const int mat  = row >> 8;
  const int i    = row & 255;
  const int c0   = kc * 8;
  float v[8];
  if (mat == 0) {
    #pragma unroll
    for (int j = 0; j < 8; ++j)
      v[j] = J0[i * NN + c0 + j] + 0.1f * Wo[i * NN + c0 + j];  // J0 + J1*Wo
  } else {
    const float* src = Wa + ((size_t)(mat - 1) * NN + i) * NN + c0;
    #pragma unroll
    for (int j = 0; j < 8; ++j) v[j] = src[j];
  }
  uint p[4];
  #pragma unroll
  for (int j = 0; j < 4; ++j) {
    _Float16 hl = (_Float16)v[2 * j];        // v_cvt_f16_f32, RNE
    _Float16 hh = (_Float16)v[2 * j + 1];
    unsigned short sl, sh;
    __builtin_memcpy(&sl, &hl, 2);
    __builtin_memcpy(&sh, &hh, 2);
    p[j] = (uint)sl | ((uint)sh << 16);
  }
  Wt[(size_t)(g * KC + kc) * 64 + lane] = make_uint4(p[0], p[1], p[2], p[3]);
}

__device__ __forceinline__ float f16lo(uint u) {
  unsigned short s = (unsigned short)(u & 0xFFFFu);
  _Float16 h; __builtin_memcpy(&h, &s, 2);
  return (float)h;
}
__device__ __forceinline__ float f16hi(uint u) {
  unsigned short s = (unsigned short)(u >> 16);
  _Float16 h; __builtin_memcpy(&h, &s, 2);
  return (float)h;
}

// unpack-and-FMA 8 packed fp16 weights against r[8]
__device__ __forceinline__ float dot8(uint4 w, float4 ra, float4 rb) {
  float s;
  s  = f16lo(w.x) * ra.x;
  s += f16hi(w.x) * ra.y;
  s += f16lo(w.y) * ra.z;
  s += f16hi(w.y) * ra.w;
  s += f16lo(w.z) * rb.x;
  s += f16hi(w.z) * rb.y;
  s += f16lo(w.w) * rb.z;
  s += f16hi(w.w) * rb.w;
  return s;
}

__global__ __launch_bounds__(NTHR, 1)
void ring_main_kernel(const float* __restrict__ act,     // [64,512,8]
                      const float* __restrict__ r_init,  // [64,256]
                      const float* __restrict__ Wd7,     // [256,256]
                      const uint4* __restrict__ Wt,      // tiled fp16 weights
                      float* __restrict__ out)           // r_hist | bump
{
  __shared__ float r_s[NN];        // current state, fp32
  __shared__ float m_s[ROWS];      // per-(mat,i) dot results
  __shared__ float cvec[NN], svec[NN];
  __shared__ float at_s[ADIM];
  __shared__ float cs_s[4][2];
  __shared__ float sums_s[3];      // sum c^2, c*s, s^2

  const int tid  = threadIdx.x;
  const int wv   = tid >> 6;
  const int lane = tid & 63;
  const int b    = blockIdx.x;

  float* out_r = out;
  float* out_b = out + (size_t)BATCH * TT * NN;

  for (int idx = tid; idx < NN; idx += NTHR) {
    cvec[idx] = Wd7[idx * NN];          // cos(theta_i)
    svec[idx] = Wd7[idx * NN + 64];     // sin(theta_i)
    r_s[idx]  = r_init[b * NN + idx];
  }
  __syncthreads();
  if (tid == 0) {
    float a = 0.f, c2 = 0.f, c = 0.f;
    for (int j = 0; j < NN; ++j) {
      const float cj = cvec[j], sj = svec[j];
      a += cj * cj; c2 += cj * sj; c += sj * sj;
    }
    sums_s[0] = a; sums_s[1] = c2; sums_s[2] = c;
  }
  __syncthreads();

  // per-wave weight stream bases (wave w owns row-groups 4w..4w+3)
  const int g0 = wv * 4;
  const uint4* base0 = Wt + (size_t)(g0 + 0) * KC * 64 + lane;
  const uint4* base1 = Wt + (size_t)(g0 + 1) * KC * 64 + lane;
  const uint4* base2 = Wt + (size_t)(g0 + 2) * KC * 64 + lane;
  const uint4* base3 = Wt + (size_t)(g0 + 3) * KC * 64 + lane;

  for (int t = 0; t < TT; ++t) {
    if (tid < ADIM) at_s[tid] = act[((size_t)b * TT + t) * ADIM + tid];

    // Phase A: stream weights, private per-lane row dots
    float a0 = 0.f, a1 = 0.f, a2 = 0.f, a3 = 0.f;
    uint4 w0 = base0[0], w1 = base1[0], w2 = base2[0], w3 = base3[0];
    #pragma unroll 4
    for (int k = 0; k < KC; ++k) {
      const float4 ra = *(const float4*)&r_s[k * 8];      // LDS broadcast
      const float4 rb = *(const float4*)&r_s[k * 8 + 4];
      const int kn = (k + 1) & (KC - 1);                  // branch-free wrap
      uint4 n0 = base0[kn * 64], n1 = base1[kn * 64];
      uint4 n2 = base2[kn * 64], n3 = base3[kn * 64];
      a0 += dot8(w0, ra, rb);
      a1 += dot8(w1, ra, rb);
      a2 += dot8(w2, ra, rb);
      a3 += dot8(w3, ra, rb);
      w0 = n0; w1 = n1; w2 = n2; w3 = n3;
    }
    m_s[(g0 + 0) * 64 + lane] = a0;
    m_s[(g0 + 1) * 64 + lane] = a1;
    m_s[(g0 + 2) * 64 + lane] = a2;
    m_s[(g0 + 3) * 64 + lane] = a3;
    __syncthreads();                      // S1: m_s/at_s ready

    // Phase B: combine + tanh-leak update + r_hist write + C/S reduce
    if (tid < NN) {
      const int i = tid;
      float rec = m_s[i];
      #pragma unroll
      for (int a = 0; a < ADIM; ++a) rec += at_s[a] * m_s[(1 + a) * NN + i];
      const float ro = r_s[i];
      const float rn = ro + 0.1f * (tanhf(rec) - ro);     // DT/TAU = 0.1
      r_s[i] = rn;
      out_r[((size_t)b * TT + t) * NN + i] = rn;
      float cp = cvec[i] * rn, sp = svec[i] * rn;
      #pragma unroll
      for (int m = 1; m < 64; m <<= 1) {
        cp += __shfl_xor(cp, m);
        sp += __shfl_xor(sp, m);
      }
      if (lane == 0) { cs_s[wv][0] = cp; cs_s[wv][1] = sp; }
    }
    __syncthreads();                      // S2: r_s/cs_s ready

    // Phase C: bump output (waves 4..8 already start next step's stream)
    if (tid < NN) {
      const int i = tid;
      const float C = cs_s[0][0] + cs_s[1][0] + cs_s[2][0] + cs_s[3][0];
      const float S = cs_s[0][1] + cs_s[1][1] + cs_s[2][1] + cs_s[3][1];
      const float n2 = sums_s[0] * C * C + 2.f * sums_s[1] * C * S
                     + sums_s[2] * S * S;
      out_b[((size_t)b * TT + t) * NN + i] =
          (cvec[i] * C + svec[i] * S) * (1.0f / sqrtf(n2));
    }
    // no sync needed here: next Phase A only reads r_s (stable since S2) and
    // writes m_s (consumed before S2); at_s is rewritten only by wave 0,
    // which passed S2; Phase C reads no buffer that Phase A writes.
  }
}

extern "C" void kernel_launch(void* const* d_in, const int* in_sizes, int n_in,
                              void* d_out, int out_size, void* d_ws, size_t ws_size,
                              hipStream_t stream) {
  const float* act    = (const float*)d_in[0];
  const float* r_init = (const float*)d_in[1];
  const float* Wo     = (const float*)d_in[2];
  const float* Wa     = (const float*)d_in[3];
  const float* J0     = (const float*)d_in[4];
  const float* Wd7    = (const float*)d_in[5];
  float* out = (float*)d_out;
  uint4* Wt  = (uint4*)d_ws;   // 2304*256 fp16 = 1.125 MiB tiled weights

  // GROUPS*KC*64 = 73728 uint4 entries, one thread each -> 288 blocks of 256
  hipLaunchKernelGGL(build_wt_kernel, dim3(288), dim3(256), 0, stream,
                     Wo, Wa, J0, Wt);
  hipLaunchKernelGGL(ring_main_kernel, dim3(BATCH), dim3(NTHR), 0, stream,
                     act, r_init, Wd7, (const uint4*)Wt, out);
}